// Round 27
// baseline (57.275 us; speedup 1.0000x reference)
//
#include <hip/hip_runtime.h>
#include <math.h>

// NSVQ: N=131072 rows, D=64, K=1024 codes (fp32).
// out (flat f32): [0,N*D) quantized; [N*D] perplexity; [N*D+1,+K) counts.
// ws layout:
//   [0,4096)         cn2k   f32[K]     2048*(||c||^2 + 512)
//   [4096,8192)      counts int[K]
//   [8192,139264)    cbf    fp16[K*64] codebook, 32x32-MFMA fragment order
// fragment order (16B entry): idx = g*256 + ks*64 + lane
//   holds code (g*32 + (lane&31)), dims ks*16 + (lane>>5)*8 + [0..8)

#define NSVQ_D 64
#define ABN 128      // rows per block (256 thr, 4 waves x 32 rows -> grid 1024, 4 blk/CU)

typedef __attribute__((ext_vector_type(8))) _Float16 half8;
typedef __attribute__((ext_vector_type(16))) float f32x16;

// ---------------- prep: codebook norms + fp16 32x32-fragment plane + zero counts ----------------
__global__ __launch_bounds__(256)
void nsvq_prep(const float* __restrict__ cb,
               ushort* __restrict__ cbf,
               float* __restrict__ cn2k, int* __restrict__ counts, int K) {
  if (blockIdx.x == 0) ((int4*)counts)[threadIdx.x] = make_int4(0, 0, 0, 0);
  int r = blockIdx.x * 256 + threadIdx.x;  // one code per thread
  if (r >= K) return;
  const float* row = cb + (long)r * NSVQ_D;
  float nrm = 0.f;
#pragma unroll
  for (int j = 0; j < 8; ++j) {            // dim block j = dims 8j..8j+7
    float4 v0 = *(const float4*)(row + j * 8);
    float4 v1 = *(const float4*)(row + j * 8 + 4);
    float f[8] = {v0.x, v0.y, v0.z, v0.w, v1.x, v1.y, v1.z, v1.w};
    half8 hv;
#pragma unroll
    for (int e = 0; e < 8; ++e) {
      nrm = fmaf(f[e], f[e], nrm);
      hv[e] = (_Float16)f[e];
    }
    // 32x32 fragment order: entry = (r>>5)*256 + (j>>1)*64 + (j&1)*32 + (r&31)
    int blk = (r >> 5) * 256 + (j >> 1) * 64 + (j & 1) * 32 + (r & 31);
    *(half8*)(cbf + blk * 8) = hv;
  }
  cn2k[r] = 2048.f * (nrm + 512.f);        // acc-init constant; scores in (0.78M, 1.72M)
}

// ---------------- fused: L2-direct codebook, 32x32x16 MFMA top-1 argmin + in-register tail ----------------
__global__ __launch_bounds__(256, 2)
void nsvq_fused(const float* __restrict__ x,
                const ushort* __restrict__ cbf,
                const float* __restrict__ cn2k,
                const float* __restrict__ rv,
                int* __restrict__ counts,
                float* __restrict__ out) {
  __shared__ uint bestLds[ABN];            // packed score|idx per row (wave-private)
  __shared__ int hist[1024];               // 4 KB
  ((int4*)hist)[threadIdx.x] = make_int4(0, 0, 0, 0);

  const int tid = threadIdx.x;
  const int lane = tid & 63;
  const int wid = tid >> 6;                // 0..3, each wave owns 32 rows
  const int l31 = lane & 31;               // code-in-group / A-row / tail row
  const int lh = lane >> 5;                // k-half / dim-half
  const long brow = (long)blockIdx.x * ABN;
  const int wrow = wid * 32;

  // ---- A fragments + keep fp32 x in regs + ||x||^2 (local 32 dims) ----
  // lane (l31, lh) holds row l31's dims {ks*16 + lh*8 + [0..8), ks=0..3}
  half8 ax[4];
  float4 xf[8];
  float xxloc = 0.f;
  const long grow = brow + wrow + l31;     // this lane's tail row
#pragma unroll
  for (int ks = 0; ks < 4; ++ks) {
    const float* xr = x + grow * NSVQ_D + ks * 16 + lh * 8;
    float4 v0 = *(const float4*)xr;
    float4 v1 = *(const float4*)(xr + 4);
    xf[ks * 2] = v0;
    xf[ks * 2 + 1] = v1;
    xxloc += v0.x * v0.x + v0.y * v0.y + v0.z * v0.z + v0.w * v0.w;
    xxloc += v1.x * v1.x + v1.y * v1.y + v1.z * v1.z + v1.w * v1.w;
    half8 h;
    h[0] = (_Float16)(v0.x * -4096.f); h[1] = (_Float16)(v0.y * -4096.f);
    h[2] = (_Float16)(v0.z * -4096.f); h[3] = (_Float16)(v0.w * -4096.f);
    h[4] = (_Float16)(v1.x * -4096.f); h[5] = (_Float16)(v1.y * -4096.f);
    h[6] = (_Float16)(v1.z * -4096.f); h[7] = (_Float16)(v1.w * -4096.f);
    ax[ks] = h;
  }

  uint u1[16];
#pragma unroll
  for (int i = 0; i < 16; ++i) u1[i] = 0xFFFFFFFFu;

  __syncthreads();                         // hist zeroed before tail atomics

  auto LOAD = [&](half8 (&B)[4], float& cn, int g) {
    const ushort* p = cbf + g * 2048 + lane * 8;
#pragma unroll
    for (int ks = 0; ks < 4; ++ks) B[ks] = *(const half8*)(p + ks * 512);
    cn = cn2k[g * 32 + l31];
  };
  auto COMPUTE = [&](const half8 (&B)[4], float cc, int g) {
    const uint kidx = (uint)(g * 32 + l31);
    f32x16 a = {cc, cc, cc, cc, cc, cc, cc, cc, cc, cc, cc, cc, cc, cc, cc, cc};
    a = __builtin_amdgcn_mfma_f32_32x32x16_f16(ax[0], B[0], a, 0, 0, 0);
    a = __builtin_amdgcn_mfma_f32_32x32x16_f16(ax[1], B[1], a, 0, 0, 0);
    a = __builtin_amdgcn_mfma_f32_32x32x16_f16(ax[2], B[2], a, 0, 0, 0);
    a = __builtin_amdgcn_mfma_f32_32x32x16_f16(ax[3], B[3], a, 0, 0, 0);
#pragma unroll
    for (int r = 0; r < 16; ++r) {
      // positive float -> raw bits monotone; one v_and_or packs score|index,
      // one v_min tracks the argmin (ties -> lowest index automatically)
      uint m = (__float_as_uint(a[r]) & 0xFFFFFC00u) | kidx;
      u1[r] = min(u1[r], m);
    }
  };

  half8 BA[4], BB[4];
  float cnA, cnB;
  LOAD(BA, cnA, 0);
  LOAD(BB, cnB, 1);

  for (int g = 0; g < 32; g += 2) {        // 32 groups x 32 codes, L2-fed
    COMPUTE(BA, cnA, g);
    LOAD(BA, cnA, (g + 2) & 31);           // tail wraps: dead values, valid addrs
    COMPUTE(BB, cnB, g + 1);
    LOAD(BB, cnB, (g + 3) & 31);
  }

  // ---- cross-lane top-1 merge; deposit packed score|idx in wave-private LDS ----
#pragma unroll
  for (int r = 0; r < 16; ++r) {
    uint a1 = u1[r];
#pragma unroll
    for (int off = 1; off < 32; off <<= 1)    // stays within 32-lane half
      a1 = min(a1, (uint)__shfl_xor((int)a1, off));
    if (l31 == 0) {
      // C/D row mapping: row = (r&3) + 8*(r>>2) + 4*lh  (verified m74/m101)
      int rowloc = (r & 3) + 8 * (r >> 2) + 4 * lh;
      bestLds[wrow + rowloc] = a1;
    }
  }
  // same-wave LDS write->read is ordered (single DS pipe, in-order); no barrier needed

  // ---- per-wave tail: lane pair (l31, l31+32) finishes row l31 in-register ----
  uint p = bestLds[wrow + l31];
  uint k = p & 1023u;
  float sraw = __uint_as_float(p & 0xFFFFFC00u);  // 2048*(||c||^2+512-2x.c), trunc <=0.22

  float4 rr[8];
  float drnd = 0.f;
#pragma unroll
  for (int ks = 0; ks < 4; ++ks) {
    const float* rp = rv + grow * NSVQ_D + ks * 16 + lh * 8;
    float4 r0 = *(const float4*)rp;
    float4 r1 = *(const float4*)(rp + 4);
    rr[ks * 2] = r0;
    rr[ks * 2 + 1] = r1;
    drnd += r0.x * r0.x + r0.y * r0.y + r0.z * r0.z + r0.w * r0.w;
    drnd += r1.x * r1.x + r1.y * r1.y + r1.z * r1.z + r1.w * r1.w;
  }
  float xx = xxloc + __shfl_xor(xxloc, 32, 64);
  drnd += __shfl_xor(drnd, 32, 64);
  // ||x-c||^2 = sraw/2048 - 512 + ||x||^2   (err ~1e-4, clamp for safety)
  float dres = fmaxf(fmaf(sraw, 1.f / 2048.f, xx - 512.f), 0.f);
  float scale = sqrtf(dres) / (sqrtf(drnd) + 1e-12f);

#pragma unroll
  for (int ks = 0; ks < 4; ++ks) {
    float* op = out + grow * NSVQ_D + ks * 16 + lh * 8;
    float4 x0 = xf[ks * 2], x1 = xf[ks * 2 + 1];
    float4 r0 = rr[ks * 2], r1 = rr[ks * 2 + 1];
    float4 o0, o1;
    o0.x = x0.x + scale * r0.x; o0.y = x0.y + scale * r0.y;
    o0.z = x0.z + scale * r0.z; o0.w = x0.w + scale * r0.w;
    o1.x = x1.x + scale * r1.x; o1.y = x1.y + scale * r1.y;
    o1.z = x1.z + scale * r1.z; o1.w = x1.w + scale * r1.w;
    *(float4*)op = o0;
    *(float4*)(op + 4) = o1;
  }
  if (lh == 0) atomicAdd(&hist[k], 1);     // one lane per row

  // ---- merge block histogram into global counts (sparse) ----
  __syncthreads();
  int v0 = hist[tid];
  int v1 = hist[tid + 256];
  int v2 = hist[tid + 512];
  int v3 = hist[tid + 768];
  if (v0) atomicAdd(&counts[tid], v0);
  if (v1) atomicAdd(&counts[tid + 256], v1);
  if (v2) atomicAdd(&counts[tid + 512], v2);
  if (v3) atomicAdd(&counts[tid + 768], v3);
}

// ---------------- perplexity + counts output ----------------
__global__ void nsvq_perp_kernel(const int* __restrict__ counts,
                                 float* __restrict__ out_tail,  // [0]=perp, [1..K]=counts
                                 float invN, int K) {
  int t = threadIdx.x;
  float v = 0.f;
  if (t < K) {
    int c = counts[t];
    out_tail[1 + t] = (float)c;
    float p = (float)c * invN;
    v = p * logf(p + 1e-12f);
  }
#pragma unroll
  for (int off = 1; off < 64; off <<= 1) v += __shfl_xor(v, off, 64);
  __shared__ float red[16];
  int wid = t >> 6;
  if ((t & 63) == 0) red[wid] = v;
  __syncthreads();
  if (t == 0) {
    float s = 0.f;
    int nw = (blockDim.x + 63) / 64;
    for (int w = 0; w < nw; ++w) s += red[w];
    out_tail[0] = expf(-s);
  }
}

extern "C" void kernel_launch(void* const* d_in, const int* in_sizes, int n_in,
                              void* d_out, int out_size, void* d_ws, size_t ws_size,
                              hipStream_t stream) {
  const float* x  = (const float*)d_in[0];
  const float* cb = (const float*)d_in[1];
  const float* rv = (const float*)d_in[2];
  float* out = (float*)d_out;

  const int D = NSVQ_D;
  const int N = in_sizes[0] / D;  // 131072
  const int K = in_sizes[1] / D;  // 1024

  float*  cn2k   = (float*)d_ws;
  int*    counts = (int*)((char*)d_ws + 4096);
  ushort* cbf    = (ushort*)((char*)d_ws + 8192);

  nsvq_prep<<<(K + 255) / 256, 256, 0, stream>>>(cb, cbf, cn2k, counts, K);
  nsvq_fused<<<N / ABN, 256, 0, stream>>>(x, cbf, cn2k, rv, counts, out);
  nsvq_perp_kernel<<<1, 1024, 0, stream>>>(counts, out + (size_t)N * D, 1.0f / (float)N, K);
}